// Round 6
// baseline (496.752 us; speedup 1.0000x reference)
//
#include <hip/hip_runtime.h>
#include <math.h>

#define Hn 256
#define NHn 4
#define HDn 64
#define DWn 32
#define DAn 32
#define DVn 32
#define DGn 64
#define Bqn 2
#define Qln 8
#define Tln 512
#define EBn 16
#define NC 16   // timesteps per LDS chunk
#define NCH 32  // chunks = Tln/NC
#define VGn 4   // blocks per (eb,h): each owns 16 v-cols

__device__ __forceinline__ float sigm(float x) { return 1.0f / (1.0f + expf(-x)); }

__device__ __forceinline__ float wsum64(float v) {
#pragma unroll
    for (int m = 32; m >= 1; m >>= 1) v += __shfl_xor(v, m, 64);
    return v;
}

// ---------------- Kernel A: per (b,t): k, kk (normalized), vraw, sv ----------------
__global__ void kA(const float* __restrict__ keyval,
                   const float* __restrict__ x_k, const float* __restrict__ x_v,
                   const float* __restrict__ Wk, const float* __restrict__ Wv,
                   const float* __restrict__ v0, const float* __restrict__ v1,
                   const float* __restrict__ v2, const float* __restrict__ k_k,
                   float* __restrict__ k_g, float* __restrict__ kk_g,
                   float* __restrict__ vraw_g, float* __restrict__ sv_g) {
    int bt = blockIdx.x;              // b*Tl + t
    int t = bt & (Tln - 1);
    int c = threadIdx.x;              // channel 0..255

    __shared__ __align__(16) float xk_s[Hn];
    __shared__ __align__(16) float xv_s[Hn];
    __shared__ float hv_s[DVn];

    float hs = keyval[bt * Hn + c];
    float pv = (t > 0) ? keyval[(bt - 1) * Hn + c] : 0.0f;
    float d = pv - hs;
    xk_s[c] = fmaf(d, x_k[c], hs);
    xv_s[c] = fmaf(d, x_v[c], hs);
    __syncthreads();

    // hv[d] = xv @ v1, threads 0..31
    if (c < DVn) {
        float acc = 0.f;
#pragma unroll 8
        for (int j = 0; j < Hn; ++j) acc = fmaf(xv_s[j], v1[j * DVn + c], acc);
        hv_s[c] = acc;
    }

    // k and vraw matvecs (row c of Wk/Wv)
    float kacc = 0.f, vacc = 0.f;
    const float4* xk4 = (const float4*)xk_s;
    const float4* xv4 = (const float4*)xv_s;
    const float4* wk4 = (const float4*)(Wk + c * Hn);
    const float4* wv4 = (const float4*)(Wv + c * Hn);
#pragma unroll 8
    for (int j = 0; j < Hn / 4; ++j) {
        float4 xa = xk4[j], wa = wk4[j];
        kacc += xa.x * wa.x + xa.y * wa.y + xa.z * wa.z + xa.w * wa.w;
        float4 xb = xv4[j], wb = wv4[j];
        vacc += xb.x * wb.x + xb.y * wb.y + xb.z * wb.z + xb.w * wb.w;
    }
    __syncthreads();

    // sv = sigmoid(v0 + hv @ v2)
    float svacc = v0[c];
#pragma unroll 8
    for (int dd = 0; dd < DVn; ++dd) svacc = fmaf(hv_s[dd], v2[dd * Hn + c], svacc);
    float sv = sigm(svacc);

    // kk = (k * k_k) normalized per head; head == wave (64 consecutive channels)
    float kkraw = kacc * k_k[c];
    float ss = wsum64(kkraw * kkraw);
    float denom = fmaxf(sqrtf(ss), 1e-12f);
    float kk = kkraw / denom;

    int o = bt * Hn + c;
    k_g[o] = kacc;
    kk_g[o] = kk;
    vraw_g[o] = vacc;
    sv_g[o] = sv;
}

// ---- Kernel B: per (eb,t): coef4 = {ew, km, ck, kk} packed, vt precomputed -------
__global__ void kB(const float* __restrict__ query, const float* __restrict__ keyval,
                   const float* __restrict__ x_w, const float* __restrict__ x_a,
                   const float* __restrict__ w0, const float* __restrict__ w1,
                   const float* __restrict__ w2, const float* __restrict__ a0,
                   const float* __restrict__ a1, const float* __restrict__ a2,
                   const float* __restrict__ k_a,
                   const float* __restrict__ k_g, const float* __restrict__ kk_g,
                   const float* __restrict__ vraw_g, const float* __restrict__ sv_g,
                   const float* __restrict__ v_first,
                   float4* __restrict__ coef4, float* __restrict__ vt_g) {
    const float NEGC = -0.60653065971263342f;  // -exp(-0.5)
    int id = blockIdx.x;               // eb*Tl + t
    int eb = id >> 9, t = id & (Tln - 1);
    int b = eb >> 3;                   // eb / Ql
    int c = threadIdx.x;

    __shared__ __align__(16) float xw_s[Hn];
    __shared__ __align__(16) float xa_s[Hn];
    __shared__ float hw_s[DWn];
    __shared__ float ha_s[DAn];

    int bt = (b << 9) + t;
    float hs = keyval[bt * Hn + c];
    float q = query[eb * Hn + c];
    float d = q - hs;
    xw_s[c] = fmaf(d, x_w[c], hs);
    xa_s[c] = fmaf(d, x_a[c], hs);
    __syncthreads();

    if (c < DWn) {
        float acc = 0.f;
#pragma unroll 8
        for (int j = 0; j < Hn; ++j) acc = fmaf(xw_s[j], w1[j * DWn + c], acc);
        hw_s[c] = tanhf(acc);
    } else if (c < DWn + DAn) {
        int dd = c - DWn;
        float acc = 0.f;
#pragma unroll 8
        for (int j = 0; j < Hn; ++j) acc = fmaf(xa_s[j], a1[j * DAn + dd], acc);
        ha_s[dd] = acc;
    }
    __syncthreads();

    float wacc = w0[c], aacc = a0[c];
#pragma unroll 8
    for (int dd = 0; dd < DWn; ++dd) {
        wacc = fmaf(hw_s[dd], w2[dd * Hn + c], wacc);
        aacc = fmaf(ha_s[dd], a2[dd * Hn + c], aacc);
    }
    float w = NEGC * sigm(wacc);
    float a = sigm(aacc);

    int obt = bt * Hn + c;
    size_t oet = (size_t)id * Hn + c;
    float kv = k_g[obt];
    float kkv = kk_g[obt];
    float ew = expf(w);
    float km = kv * fmaf(a - 1.0f, k_a[c], 1.0f);
    float ck = kkv * a;
    coef4[oet] = make_float4(ew, km, ck, kkv);

    float vr = vraw_g[obt];
    float sv = sv_g[obt];
    float vf = v_first[oet];
    vt_g[oet] = fmaf(vf - vr, sv, vr);
}

// ---- Kernel R: per eb (t=T-1 only): r, g(gate), s_h bonus scalars ---------------
__global__ void kR(const float* __restrict__ query, const float* __restrict__ keyval,
                   const float* __restrict__ x_r, const float* __restrict__ x_g,
                   const float* __restrict__ Wr, const float* __restrict__ g1,
                   const float* __restrict__ g2, const float* __restrict__ r_k,
                   const float4* __restrict__ coef4,
                   float* __restrict__ r_g, float* __restrict__ g_g,
                   float* __restrict__ sh_g) {
    int eb = blockIdx.x;
    int b = eb >> 3;
    int c = threadIdx.x;

    __shared__ __align__(16) float xr_s[Hn];
    __shared__ __align__(16) float xg_s[Hn];
    __shared__ float hg_s[DGn];

    int btl = (b * Tln + (Tln - 1)) * Hn;
    float hs = keyval[btl + c];
    float q = query[eb * Hn + c];
    float d = q - hs;
    xr_s[c] = fmaf(d, x_r[c], hs);
    xg_s[c] = fmaf(d, x_g[c], hs);
    __syncthreads();

    float racc = 0.f;
    {
        const float4* xr4 = (const float4*)xr_s;
        const float4* wr4 = (const float4*)(Wr + c * Hn);
#pragma unroll 8
        for (int j = 0; j < Hn / 4; ++j) {
            float4 xa = xr4[j], wa = wr4[j];
            racc += xa.x * wa.x + xa.y * wa.y + xa.z * wa.z + xa.w * wa.w;
        }
    }

    if (c < DGn) {
        float gacc = 0.f;
#pragma unroll 8
        for (int j = 0; j < Hn; ++j) gacc = fmaf(xg_s[j], g1[j * DGn + c], gacc);
        hg_s[c] = sigm(gacc);
    }
    __syncthreads();

    float gv = 0.f;
#pragma unroll 8
    for (int dd = 0; dd < DGn; ++dd) gv = fmaf(hg_s[dd], g2[dd * Hn + c], gv);

    // s_h = sum over head channels of r * km(T-1) * r_k
    float kmv = coef4[((size_t)(eb * Tln + (Tln - 1))) * Hn + c].y;
    float part = wsum64(racc * kmv * r_k[c]);

    r_g[eb * Hn + c] = racc;
    g_g[eb * Hn + c] = gv;
    if ((c & 63) == 0) sh_g[eb * NHn + (c >> 6)] = part;
}

// ---- Kernel C: scan. 4 blocks (128 thr = 2 waves) per (eb,h); block owns 16 v. --
// Wave w: lane = g*8+vv -> S rows 8g..8g+7 (rotated: S[m] = row (g<<3)|((m+g)&7)),
// v col = vg*16 + w*8 + vv. LDS holds ALL 64 rows' coefs per step (identity
// storage, rotated read order -> bank-free); vt staged only for the block's 16
// cols. Chunked double-buffer, reg-staged prefetch one chunk ahead (raw
// s_barrier + manual lgkmcnt; vmcnt never drained to 0 at barriers).
__global__ __launch_bounds__(128) void kScan(
    const float4* __restrict__ coef, const float* __restrict__ vt_g,
    const float* __restrict__ r_g, float* __restrict__ o_raw) {
    int blk = blockIdx.x;            // ((eb*NH)+h)*VGn + vg
    int eb = blk >> 4, h = (blk >> 2) & 3, vg = blk & 3;
    int tid = threadIdx.x;
    int w = tid >> 6, lane = tid & 63;
    int g = lane >> 3, vv = lane & 7;

    __shared__ __align__(16) float4 cs[2][NC][64];   // 2 x 16 KB
    __shared__ __align__(16) float  vs[2][NC][16];   // 2 x 1 KB

    const size_t gstep0 = ((size_t)eb * Tln) * Hn + h * HDn;  // + t*Hn + row
    // coef staging: 8 iters x (2 steps x 64 rows); srow=lane, soff=w
    const int srow = lane, soff = w;
    // vt staging: 16 steps x 16 cols; 2 per thread
    const int vts = tid >> 4;        // 0..7
    const int vtc = tid & 15;
    const int vcol0 = vg * 16;

    float4 rcA[8], rcB[8];
    float  rvA0, rvA1, rvB0, rvB1;

#define LOADC(SET, CHUNK)                                                     \
    {                                                                         \
        int cc_ = (CHUNK) < NCH ? (CHUNK) : NCH - 1;                          \
        size_t gb_ = gstep0 + (size_t)(cc_ * NC) * Hn;                        \
        _Pragma("unroll")                                                     \
        for (int it = 0; it < 8; ++it)                                        \
            rc##SET[it] = coef[gb_ + (size_t)(2 * it + soff) * Hn + srow];    \
        rv##SET##0 = vt_g[gb_ + (size_t)vts * Hn + vcol0 + vtc];              \
        rv##SET##1 = vt_g[gb_ + (size_t)(vts + 8) * Hn + vcol0 + vtc];        \
    }

#define STOREC(SET, B)                                                        \
    {                                                                         \
        _Pragma("unroll")                                                     \
        for (int it = 0; it < 8; ++it)                                        \
            cs[B][2 * it + soff][srow] = rc##SET[it];                         \
        vs[B][vts][vtc]     = rv##SET##0;                                     \
        vs[B][vts + 8][vtc] = rv##SET##1;                                     \
    }

    // per-lane read slots (identity storage, rotated read order)
    const int o0 = (g << 3) | ((0 + g) & 7);
    const int o1 = (g << 3) | ((1 + g) & 7);
    const int o2 = (g << 3) | ((2 + g) & 7);
    const int o3 = (g << 3) | ((3 + g) & 7);
    const int o4 = (g << 3) | ((4 + g) & 7);
    const int o5 = (g << 3) | ((5 + g) & 7);
    const int o6 = (g << 3) | ((6 + g) & 7);
    const int o7 = (g << 3) | ((7 + g) & 7);
    const int vslot = (w << 3) | vv;

    float S[8];
#pragma unroll
    for (int i = 0; i < 8; ++i) S[i] = 0.f;

#define COMPUTE(B)                                                            \
    _Pragma("unroll")                                                         \
    for (int s = 0; s < NC; ++s) {                                            \
        float vt = vs[B][s][vslot];                                           \
        float4 c0 = cs[B][s][o0]; float4 c1 = cs[B][s][o1];                   \
        float4 c2 = cs[B][s][o2]; float4 c3 = cs[B][s][o3];                   \
        float4 c4 = cs[B][s][o4]; float4 c5 = cs[B][s][o5];                   \
        float4 c6 = cs[B][s][o6]; float4 c7 = cs[B][s][o7];                   \
        float p0 = c0.w * S[0];  p0 = fmaf(c2.w, S[2], p0);                   \
        float p1 = c1.w * S[1];  p1 = fmaf(c3.w, S[3], p1);                   \
        float p2 = c4.w * S[4];  p2 = fmaf(c6.w, S[6], p2);                   \
        float p3 = c5.w * S[5];  p3 = fmaf(c7.w, S[7], p3);                   \
        float p = (p0 + p1) + (p2 + p3);                                      \
        p += __shfl_xor(p, 8, 64);                                            \
        p += __shfl_xor(p, 16, 64);                                           \
        p += __shfl_xor(p, 32, 64);                                           \
        float naS = -p;                                                       \
        S[0] = fmaf(S[0], c0.x, fmaf(c0.y, vt, c0.z * naS));                  \
        S[1] = fmaf(S[1], c1.x, fmaf(c1.y, vt, c1.z * naS));                  \
        S[2] = fmaf(S[2], c2.x, fmaf(c2.y, vt, c2.z * naS));                  \
        S[3] = fmaf(S[3], c3.x, fmaf(c3.y, vt, c3.z * naS));                  \
        S[4] = fmaf(S[4], c4.x, fmaf(c4.y, vt, c4.z * naS));                  \
        S[5] = fmaf(S[5], c5.x, fmaf(c5.y, vt, c5.z * naS));                  \
        S[6] = fmaf(S[6], c6.x, fmaf(c6.y, vt, c6.z * naS));                  \
        S[7] = fmaf(S[7], c7.x, fmaf(c7.y, vt, c7.z * naS));                  \
    }

    // prologue
    LOADC(A, 0);
    STOREC(A, 0);           // compiler inserts vmcnt wait for A regs
    LOADC(B, 1);
    asm volatile("s_waitcnt lgkmcnt(0)" ::: "memory");
    __builtin_amdgcn_s_barrier();

    for (int c = 0; c < NCH; c += 2) {
        COMPUTE(0);                     // chunk c from buf0
        LOADC(A, c + 2);                // issue c+2 (arrives during next compute)
        STOREC(B, 1);                   // chunk c+1 -> buf1 (waits B's vmcnt only)
        asm volatile("s_waitcnt lgkmcnt(0)" ::: "memory");
        __builtin_amdgcn_s_barrier();   // buf1 visible; all done reading buf0
        COMPUTE(1);                     // chunk c+1 from buf1
        LOADC(B, c + 3);
        STOREC(A, 0);                   // chunk c+2 -> buf0
        asm volatile("s_waitcnt lgkmcnt(0)" ::: "memory");
        __builtin_amdgcn_s_barrier();
    }

    // final: o[v] = sum_k r[k] * S[k][v]; S[m] holds row o_m (== slot value).
    const float* rr = r_g + eb * Hn + h * HDn;
    float op = 0.f;
    op = fmaf(rr[o0], S[0], op);
    op = fmaf(rr[o1], S[1], op);
    op = fmaf(rr[o2], S[2], op);
    op = fmaf(rr[o3], S[3], op);
    op = fmaf(rr[o4], S[4], op);
    op = fmaf(rr[o5], S[5], op);
    op = fmaf(rr[o6], S[6], op);
    op = fmaf(rr[o7], S[7], op);
    op += __shfl_xor(op, 8, 64);
    op += __shfl_xor(op, 16, 64);
    op += __shfl_xor(op, 32, 64);
    if (lane < 8) o_raw[eb * Hn + h * HDn + vg * 16 + (w << 3) + lane] = op;

#undef LOADC
#undef STOREC
#undef COMPUTE
}

// ---- Kernel D: groupnorm + bonus + gate, then @ Wo.T ---------------------------
__global__ void kD(const float* __restrict__ o_raw, const float* __restrict__ gn_w,
                   const float* __restrict__ gn_b, const float* __restrict__ sh_g,
                   const float* __restrict__ vt_g, const float* __restrict__ g_g,
                   const float* __restrict__ Wo, float* __restrict__ out) {
    const float EPSC = 64e-5f;  // HD * 1e-5
    int eb = blockIdx.x;
    int c = threadIdx.x;
    __shared__ __align__(16) float o_s[Hn];

    float o = o_raw[eb * Hn + c];
    float mu = wsum64(o) * (1.0f / HDn);
    float dev = o - mu;
    float var = wsum64(dev * dev) * (1.0f / HDn);
    float og = dev * rsqrtf(var + EPSC) * gn_w[c] + gn_b[c];

    float sh = sh_g[eb * NHn + (c >> 6)];
    float vtl = vt_g[((size_t)(eb * Tln + (Tln - 1))) * Hn + c];
    float o2 = fmaf(sh, vtl, og);
    o_s[c] = o2 * g_g[eb * Hn + c];
    __syncthreads();

    float acc = 0.f;
    const float4* o4 = (const float4*)o_s;
    const float4* w4 = (const float4*)(Wo + c * Hn);
#pragma unroll 8
    for (int j = 0; j < Hn / 4; ++j) {
        float4 xa = o4[j], wa = w4[j];
        acc += xa.x * wa.x + xa.y * wa.y + xa.z * wa.z + xa.w * wa.w;
    }
    out[eb * Hn + c] = acc;
}

extern "C" void kernel_launch(void* const* d_in, const int* in_sizes, int n_in,
                              void* d_out, int out_size, void* d_ws, size_t ws_size,
                              hipStream_t stream) {
    const float* query  = (const float*)d_in[0];
    const float* keyval = (const float*)d_in[1];
    const float* v_first= (const float*)d_in[2];
    const float* x_r = (const float*)d_in[3];
    const float* x_w = (const float*)d_in[4];
    const float* x_k = (const float*)d_in[5];
    const float* x_v = (const float*)d_in[6];
    const float* x_a = (const float*)d_in[7];
    const float* x_g = (const float*)d_in[8];
    const float* w0  = (const float*)d_in[9];
    const float* w1  = (const float*)d_in[10];
    const float* w2  = (const float*)d_in[11];
    const float* a0  = (const float*)d_in[12];
    const float* a1  = (const float*)d_in[13];
    const float* a2  = (const float*)d_in[14];
    const float* v0  = (const float*)d_in[15];
    const float* v1  = (const float*)d_in[16];
    const float* v2  = (const float*)d_in[17];
    const float* g1  = (const float*)d_in[18];
    const float* g2  = (const float*)d_in[19];
    const float* k_k = (const float*)d_in[20];
    const float* k_a = (const float*)d_in[21];
    const float* r_k = (const float*)d_in[22];
    const float* Wr  = (const float*)d_in[23];
    const float* Wk  = (const float*)d_in[24];
    const float* Wv  = (const float*)d_in[25];
    const float* Wo  = (const float*)d_in[26];
    const float* gn_w= (const float*)d_in[27];
    const float* gn_b= (const float*)d_in[28];

    float* ws = (float*)d_ws;
    const size_t BTH = (size_t)Bqn * Tln * Hn;     // 262144
    const size_t ETH = (size_t)EBn * Tln * Hn;     // 2097152

    float4* coef4 = (float4*)ws;                   // 4*ETH floats (16B-aligned base)
    float* vt_g   = ws + 4 * ETH;                  // ETH
    float* k_g    = ws + 5 * ETH;                  // BTH
    float* kk_g   = ws + 5 * ETH + BTH;
    float* vraw_g = ws + 5 * ETH + 2 * BTH;
    float* sv_g   = ws + 5 * ETH + 3 * BTH;
    float* r_g    = ws + 5 * ETH + 4 * BTH;        // EB*H
    float* g_g    = r_g + EBn * Hn;
    float* sh_g   = g_g + EBn * Hn;                // EB*NH
    float* o_raw  = sh_g + EBn * NHn;              // EB*H

    kA<<<Bqn * Tln, Hn, 0, stream>>>(keyval, x_k, x_v, Wk, Wv, v0, v1, v2, k_k,
                                     k_g, kk_g, vraw_g, sv_g);
    kB<<<EBn * Tln, Hn, 0, stream>>>(query, keyval, x_w, x_a, w0, w1, w2, a0, a1, a2,
                                     k_a, k_g, kk_g, vraw_g, sv_g, v_first,
                                     coef4, vt_g);
    kR<<<EBn, Hn, 0, stream>>>(query, keyval, x_r, x_g, Wr, g1, g2, r_k, coef4,
                               r_g, g_g, sh_g);
    kScan<<<EBn * NHn * VGn, 128, 0, stream>>>(coef4, vt_g, r_g, o_raw);
    kD<<<EBn, Hn, 0, stream>>>(o_raw, gn_w, gn_b, sh_g, vt_g, g_g, Wo, (float*)d_out);
}

// Round 8
// 431.063 us; speedup vs baseline: 1.1524x; 1.1524x over previous
//
#include <hip/hip_runtime.h>
#include <math.h>

#define Hn 256
#define NHn 4
#define HDn 64
#define DWn 32
#define DAn 32
#define DVn 32
#define DGn 64
#define Bqn 2
#define Qln 8
#define Tln 512
#define EBn 16
#define NC 16   // timesteps per LDS chunk
#define NCH 32  // chunks = Tln/NC
#define VGn 4   // blocks per (eb,h): each owns 16 v-cols

__device__ __forceinline__ float sigm(float x) { return 1.0f / (1.0f + expf(-x)); }

__device__ __forceinline__ float wsum64(float v) {
#pragma unroll
    for (int m = 32; m >= 1; m >>= 1) v += __shfl_xor(v, m, 64);
    return v;
}

// async global->LDS: global addr is per-lane, LDS dest is wave-uniform base + lane*size
__device__ __forceinline__ void gll16(const float4* g, float4* l) {
    __builtin_amdgcn_global_load_lds(
        (const __attribute__((address_space(1))) unsigned int*)g,
        (__attribute__((address_space(3))) unsigned int*)l, 16, 0, 0);
}
__device__ __forceinline__ void gll4(const float* g, float* l) {
    __builtin_amdgcn_global_load_lds(
        (const __attribute__((address_space(1))) unsigned int*)g,
        (__attribute__((address_space(3))) unsigned int*)l, 4, 0, 0);
}

// ---------------- Kernel A: per (b,t): k, kk (normalized), vraw, sv ----------------
__global__ void kA(const float* __restrict__ keyval,
                   const float* __restrict__ x_k, const float* __restrict__ x_v,
                   const float* __restrict__ Wk, const float* __restrict__ Wv,
                   const float* __restrict__ v0, const float* __restrict__ v1,
                   const float* __restrict__ v2, const float* __restrict__ k_k,
                   float* __restrict__ k_g, float* __restrict__ kk_g,
                   float* __restrict__ vraw_g, float* __restrict__ sv_g) {
    int bt = blockIdx.x;              // b*Tl + t
    int t = bt & (Tln - 1);
    int c = threadIdx.x;              // channel 0..255

    __shared__ __align__(16) float xk_s[Hn];
    __shared__ __align__(16) float xv_s[Hn];
    __shared__ float hv_s[DVn];

    float hs = keyval[bt * Hn + c];
    float pv = (t > 0) ? keyval[(bt - 1) * Hn + c] : 0.0f;
    float d = pv - hs;
    xk_s[c] = fmaf(d, x_k[c], hs);
    xv_s[c] = fmaf(d, x_v[c], hs);
    __syncthreads();

    // hv[d] = xv @ v1, threads 0..31
    if (c < DVn) {
        float acc = 0.f;
#pragma unroll 8
        for (int j = 0; j < Hn; ++j) acc = fmaf(xv_s[j], v1[j * DVn + c], acc);
        hv_s[c] = acc;
    }

    // k and vraw matvecs (row c of Wk/Wv)
    float kacc = 0.f, vacc = 0.f;
    const float4* xk4 = (const float4*)xk_s;
    const float4* xv4 = (const float4*)xv_s;
    const float4* wk4 = (const float4*)(Wk + c * Hn);
    const float4* wv4 = (const float4*)(Wv + c * Hn);
#pragma unroll 8
    for (int j = 0; j < Hn / 4; ++j) {
        float4 xa = xk4[j], wa = wk4[j];
        kacc += xa.x * wa.x + xa.y * wa.y + xa.z * wa.z + xa.w * wa.w;
        float4 xb = xv4[j], wb = wv4[j];
        vacc += xb.x * wb.x + xb.y * wb.y + xb.z * wb.z + xb.w * wb.w;
    }
    __syncthreads();

    // sv = sigmoid(v0 + hv @ v2)
    float svacc = v0[c];
#pragma unroll 8
    for (int dd = 0; dd < DVn; ++dd) svacc = fmaf(hv_s[dd], v2[dd * Hn + c], svacc);
    float sv = sigm(svacc);

    // kk = (k * k_k) normalized per head; head == wave (64 consecutive channels)
    float kkraw = kacc * k_k[c];
    float ss = wsum64(kkraw * kkraw);
    float denom = fmaxf(sqrtf(ss), 1e-12f);
    float kk = kkraw / denom;

    int o = bt * Hn + c;
    k_g[o] = kacc;
    kk_g[o] = kk;
    vraw_g[o] = vacc;
    sv_g[o] = sv;
}

// ---- Kernel B: per (eb,t): coef4 = {ew, km, ck, kk} packed, vt precomputed -------
__global__ void kB(const float* __restrict__ query, const float* __restrict__ keyval,
                   const float* __restrict__ x_w, const float* __restrict__ x_a,
                   const float* __restrict__ w0, const float* __restrict__ w1,
                   const float* __restrict__ w2, const float* __restrict__ a0,
                   const float* __restrict__ a1, const float* __restrict__ a2,
                   const float* __restrict__ k_a,
                   const float* __restrict__ k_g, const float* __restrict__ kk_g,
                   const float* __restrict__ vraw_g, const float* __restrict__ sv_g,
                   const float* __restrict__ v_first,
                   float4* __restrict__ coef4, float* __restrict__ vt_g) {
    const float NEGC = -0.60653065971263342f;  // -exp(-0.5)
    int id = blockIdx.x;               // eb*Tl + t
    int eb = id >> 9, t = id & (Tln - 1);
    int b = eb >> 3;                   // eb / Ql
    int c = threadIdx.x;

    __shared__ __align__(16) float xw_s[Hn];
    __shared__ __align__(16) float xa_s[Hn];
    __shared__ float hw_s[DWn];
    __shared__ float ha_s[DAn];

    int bt = (b << 9) + t;
    float hs = keyval[bt * Hn + c];
    float q = query[eb * Hn + c];
    float d = q - hs;
    xw_s[c] = fmaf(d, x_w[c], hs);
    xa_s[c] = fmaf(d, x_a[c], hs);
    __syncthreads();

    if (c < DWn) {
        float acc = 0.f;
#pragma unroll 8
        for (int j = 0; j < Hn; ++j) acc = fmaf(xw_s[j], w1[j * DWn + c], acc);
        hw_s[c] = tanhf(acc);
    } else if (c < DWn + DAn) {
        int dd = c - DWn;
        float acc = 0.f;
#pragma unroll 8
        for (int j = 0; j < Hn; ++j) acc = fmaf(xa_s[j], a1[j * DAn + dd], acc);
        ha_s[dd] = acc;
    }
    __syncthreads();

    float wacc = w0[c], aacc = a0[c];
#pragma unroll 8
    for (int dd = 0; dd < DWn; ++dd) {
        wacc = fmaf(hw_s[dd], w2[dd * Hn + c], wacc);
        aacc = fmaf(ha_s[dd], a2[dd * Hn + c], aacc);
    }
    float w = NEGC * sigm(wacc);
    float a = sigm(aacc);

    int obt = bt * Hn + c;
    size_t oet = (size_t)id * Hn + c;
    float kv = k_g[obt];
    float kkv = kk_g[obt];
    float ew = expf(w);
    float km = kv * fmaf(a - 1.0f, k_a[c], 1.0f);
    float ck = kkv * a;
    coef4[oet] = make_float4(ew, km, ck, kkv);

    float vr = vraw_g[obt];
    float sv = sv_g[obt];
    float vf = v_first[oet];
    vt_g[oet] = fmaf(vf - vr, sv, vr);
}

// ---- Kernel R: per eb (t=T-1 only): r, g(gate), s_h bonus scalars ---------------
__global__ void kR(const float* __restrict__ query, const float* __restrict__ keyval,
                   const float* __restrict__ x_r, const float* __restrict__ x_g,
                   const float* __restrict__ Wr, const float* __restrict__ g1,
                   const float* __restrict__ g2, const float* __restrict__ r_k,
                   const float4* __restrict__ coef4,
                   float* __restrict__ r_g, float* __restrict__ g_g,
                   float* __restrict__ sh_g) {
    int eb = blockIdx.x;
    int b = eb >> 3;
    int c = threadIdx.x;

    __shared__ __align__(16) float xr_s[Hn];
    __shared__ __align__(16) float xg_s[Hn];
    __shared__ float hg_s[DGn];

    int btl = (b * Tln + (Tln - 1)) * Hn;
    float hs = keyval[btl + c];
    float q = query[eb * Hn + c];
    float d = q - hs;
    xr_s[c] = fmaf(d, x_r[c], hs);
    xg_s[c] = fmaf(d, x_g[c], hs);
    __syncthreads();

    float racc = 0.f;
    {
        const float4* xr4 = (const float4*)xr_s;
        const float4* wr4 = (const float4*)(Wr + c * Hn);
#pragma unroll 8
        for (int j = 0; j < Hn / 4; ++j) {
            float4 xa = xr4[j], wa = wr4[j];
            racc += xa.x * wa.x + xa.y * wa.y + xa.z * wa.z + xa.w * wa.w;
        }
    }

    if (c < DGn) {
        float gacc = 0.f;
#pragma unroll 8
        for (int j = 0; j < Hn; ++j) gacc = fmaf(xg_s[j], g1[j * DGn + c], gacc);
        hg_s[c] = sigm(gacc);
    }
    __syncthreads();

    float gv = 0.f;
#pragma unroll 8
    for (int dd = 0; dd < DGn; ++dd) gv = fmaf(hg_s[dd], g2[dd * Hn + c], gv);

    // s_h = sum over head channels of r * km(T-1) * r_k
    float kmv = coef4[((size_t)(eb * Tln + (Tln - 1))) * Hn + c].y;
    float part = wsum64(racc * kmv * r_k[c]);

    r_g[eb * Hn + c] = racc;
    g_g[eb * Hn + c] = gv;
    if ((c & 63) == 0) sh_g[eb * NHn + (c >> 6)] = part;
}

// ---- Kernel C: scan. 4 blocks (128 thr = 2 waves) per (eb,h); block owns 16 v. --
// Staging via async global_load_lds (no reg staging -> no spills): per wave per
// chunk 10 loads (8 coef b128 + 2 vt b32), double-buffered with counted
// s_waitcnt vmcnt(10) (never drained to 0) + raw s_barrier. XCD swizzle: the 4
// vg-blocks of one (eb,h) land on the same XCD (shared-L2 coef streaming).
__global__ __launch_bounds__(128) void kScan(
    const float4* __restrict__ coef, const float* __restrict__ vt_g,
    const float* __restrict__ r_g, float* __restrict__ o_raw) {
    int pid = blockIdx.x;                 // 256 blocks; XCD = pid%8 (round-robin)
    int xcd = pid & 7, slot = pid >> 3;   // slot 0..31
    int ehid = (xcd << 3) | (slot >> 2);  // 0..63 -> (eb,h), fixed XCD per ehid
    int vg = slot & 3;
    int eb = ehid >> 2, h = ehid & 3;

    int tid = threadIdx.x;
    int w = tid >> 6, lane = tid & 63;
    int g = lane >> 3, vv = lane & 7;

    __shared__ __align__(16) float4 cs[2][NC][64];   // 2 x 16 KB
    __shared__ __align__(16) float  vs[2][NC][16];   // 2 x 1 KB

    const size_t gstep0 = ((size_t)eb * Tln) * Hn + h * HDn;  // + t*Hn + row
    const int soff = w;              // wave w stages steps 2*it+w
    const int vts = tid >> 4;        // 0..7
    const int vtc = tid & 15;
    const int vcol0 = vg * 16;

    // issue async loads for CHUNK into buffer B (10 per wave)
#define ISSUE(CHUNK, B)                                                       \
    {                                                                         \
        int cc_ = (CHUNK) < NCH ? (CHUNK) : NCH - 1;                          \
        size_t gb_ = gstep0 + (size_t)(cc_ * NC) * Hn;                        \
        _Pragma("unroll")                                                     \
        for (int it = 0; it < 8; ++it)                                        \
            gll16(coef + gb_ + (size_t)(2 * it + soff) * Hn + lane,           \
                  &cs[B][2 * it + soff][0]);                                  \
        float* vb_ = (float*)vs[B];                                           \
        gll4(vt_g + gb_ + (size_t)vts * Hn + vcol0 + vtc, vb_ + (w << 6));    \
        gll4(vt_g + gb_ + (size_t)(vts + 8) * Hn + vcol0 + vtc,               \
             vb_ + 128 + (w << 6));                                           \
    }

    // per-lane read slots (identity storage, rotated read order -> bank-free)
    const int o0 = (g << 3) | ((0 + g) & 7);
    const int o1 = (g << 3) | ((1 + g) & 7);
    const int o2 = (g << 3) | ((2 + g) & 7);
    const int o3 = (g << 3) | ((3 + g) & 7);
    const int o4 = (g << 3) | ((4 + g) & 7);
    const int o5 = (g << 3) | ((5 + g) & 7);
    const int o6 = (g << 3) | ((6 + g) & 7);
    const int o7 = (g << 3) | ((7 + g) & 7);
    const int vslot = (w << 3) | vv;

    float S[8];
#pragma unroll
    for (int i = 0; i < 8; ++i) S[i] = 0.f;

#define COMPUTE(B)                                                            \
    _Pragma("unroll")                                                         \
    for (int s = 0; s < NC; ++s) {                                            \
        float vt = vs[B][s][vslot];                                           \
        float4 c0 = cs[B][s][o0]; float4 c1 = cs[B][s][o1];                   \
        float4 c2 = cs[B][s][o2]; float4 c3 = cs[B][s][o3];                   \
        float4 c4 = cs[B][s][o4]; float4 c5 = cs[B][s][o5];                   \
        float4 c6 = cs[B][s][o6]; float4 c7 = cs[B][s][o7];                   \
        float p0 = c0.w * S[0];  p0 = fmaf(c2.w, S[2], p0);                   \
        float p1 = c1.w * S[1];  p1 = fmaf(c3.w, S[3], p1);                   \
        float p2 = c4.w * S[4];  p2 = fmaf(c6.w, S[6], p2);                   \
        float p3 = c5.w * S[5];  p3 = fmaf(c7.w, S[7], p3);                   \
        float p = (p0 + p1) + (p2 + p3);                                      \
        p += __shfl_xor(p, 8, 64);                                            \
        p += __shfl_xor(p, 16, 64);                                           \
        p += __shfl_xor(p, 32, 64);                                           \
        float naS = -p;                                                       \
        S[0] = fmaf(S[0], c0.x, fmaf(c0.y, vt, c0.z * naS));                  \
        S[1] = fmaf(S[1], c1.x, fmaf(c1.y, vt, c1.z * naS));                  \
        S[2] = fmaf(S[2], c2.x, fmaf(c2.y, vt, c2.z * naS));                  \
        S[3] = fmaf(S[3], c3.x, fmaf(c3.y, vt, c3.z * naS));                  \
        S[4] = fmaf(S[4], c4.x, fmaf(c4.y, vt, c4.z * naS));                  \
        S[5] = fmaf(S[5], c5.x, fmaf(c5.y, vt, c5.z * naS));                  \
        S[6] = fmaf(S[6], c6.x, fmaf(c6.y, vt, c6.z * naS));                  \
        S[7] = fmaf(S[7], c7.x, fmaf(c7.y, vt, c7.z * naS));                  \
    }

    // prologue: chunk0 -> buf0, chunk1 -> buf1 (20 in flight), wait chunk0 only
    ISSUE(0, 0)
    ISSUE(1, 1)
    asm volatile("s_waitcnt vmcnt(10)" ::: "memory");
    __builtin_amdgcn_s_barrier();

    for (int c = 0; c < NCH; c += 2) {
        COMPUTE(0)                            // chunk c from buf0 (c+1 in flight)
        __builtin_amdgcn_s_barrier();         // all waves done reading buf0
        ISSUE(c + 2, 0)                       // 20 in flight
        asm volatile("s_waitcnt vmcnt(10)" ::: "memory");  // own chunk c+1 landed
        __builtin_amdgcn_s_barrier();         // every wave's c+1 landed
        COMPUTE(1)                            // chunk c+1 from buf1
        __builtin_amdgcn_s_barrier();
        ISSUE(c + 3, 1)
        asm volatile("s_waitcnt vmcnt(10)" ::: "memory");  // chunk c+2 landed
        __builtin_amdgcn_s_barrier();
    }

    // final: o[v] = sum_k r[k] * S[k][v]; S[m] holds row o_m (== slot value).
    const float* rr = r_g + eb * Hn + h * HDn;
    float op = 0.f;
    op = fmaf(rr[o0], S[0], op);
    op = fmaf(rr[o1], S[1], op);
    op = fmaf(rr[o2], S[2], op);
    op = fmaf(rr[o3], S[3], op);
    op = fmaf(rr[o4], S[4], op);
    op = fmaf(rr[o5], S[5], op);
    op = fmaf(rr[o6], S[6], op);
    op = fmaf(rr[o7], S[7], op);
    op += __shfl_xor(op, 8, 64);
    op += __shfl_xor(op, 16, 64);
    op += __shfl_xor(op, 32, 64);
    if (lane < 8) o_raw[eb * Hn + h * HDn + vg * 16 + (w << 3) + lane] = op;

#undef ISSUE
#undef COMPUTE
}

// ---- Kernel D: groupnorm + bonus + gate, then @ Wo.T ---------------------------
__global__ void kD(const float* __restrict__ o_raw, const float* __restrict__ gn_w,
                   const float* __restrict__ gn_b, const float* __restrict__ sh_g,
                   const float* __restrict__ vt_g, const float* __restrict__ g_g,
                   const float* __restrict__ Wo, float* __restrict__ out) {
    const float EPSC = 64e-5f;  // HD * 1e-5
    int eb = blockIdx.x;
    int c = threadIdx.x;
    __shared__ __align__(16) float o_s[Hn];

    float o = o_raw[eb * Hn + c];
    float mu = wsum64(o) * (1.0f / HDn);
    float dev = o - mu;
    float var = wsum64(dev * dev) * (1.0f / HDn);
    float og = dev * rsqrtf(var + EPSC) * gn_w[c] + gn_b[c];

    float sh = sh_g[eb * NHn + (c >> 6)];
    float vtl = vt_g[((size_t)(eb * Tln + (Tln - 1))) * Hn + c];
    float o2 = fmaf(sh, vtl, og);
    o_s[c] = o2 * g_g[eb * Hn + c];
    __syncthreads();

    float acc = 0.f;
    const float4* o4 = (const float4*)o_s;
    const float4* w4 = (const float4*)(Wo + c * Hn);
#pragma unroll 8
    for (int j = 0; j < Hn / 4; ++j) {
        float4 xa = o4[j], wa = w4[j];
        acc += xa.x * wa.x + xa.y * wa.y + xa.z * wa.z + xa.w * wa.w;
    }
    out[eb * Hn + c] = acc;
}

extern "C" void kernel_launch(void* const* d_in, const int* in_sizes, int n_in,
                              void* d_out, int out_size, void* d_ws, size_t ws_size,
                              hipStream_t stream) {
    const float* query  = (const float*)d_in[0];
    const float* keyval = (const float*)d_in[1];
    const float* v_first= (const float*)d_in[2];
    const float* x_r = (const float*)d_in[3];
    const float* x_w = (const float*)d_in[4];
    const float* x_k = (const float*)d_in[5];
    const float* x_v = (const float*)d_in[6];
    const float* x_a = (const float*)d_in[7];
    const float* x_g = (const float*)d_in[8];
    const float* w0  = (const float*)d_in[9];
    const float* w1  = (const float*)d_in[10];
    const float* w2  = (const float*)d_in[11];
    const float* a0  = (const float*)d_in[12];
    const float* a1  = (const float*)d_in[13];
    const float* a2  = (const float*)d_in[14];
    const float* v0  = (const float*)d_in[15];
    const float* v1  = (const float*)d_in[16];
    const float* v2  = (const float*)d_in[17];
    const float* g1  = (const float*)d_in[18];
    const float* g2  = (const float*)d_in[19];
    const float* k_k = (const float*)d_in[20];
    const float* k_a = (const float*)d_in[21];
    const float* r_k = (const float*)d_in[22];
    const float* Wr  = (const float*)d_in[23];
    const float* Wk  = (const float*)d_in[24];
    const float* Wv  = (const float*)d_in[25];
    const float* Wo  = (const float*)d_in[26];
    const float* gn_w= (const float*)d_in[27];
    const float* gn_b= (const float*)d_in[28];

    float* ws = (float*)d_ws;
    const size_t BTH = (size_t)Bqn * Tln * Hn;     // 262144
    const size_t ETH = (size_t)EBn * Tln * Hn;     // 2097152

    float4* coef4 = (float4*)ws;                   // 4*ETH floats (16B-aligned base)
    float* vt_g   = ws + 4 * ETH;                  // ETH
    float* k_g    = ws + 5 * ETH;                  // BTH
    float* kk_g   = ws + 5 * ETH + BTH;
    float* vraw_g = ws + 5 * ETH + 2 * BTH;
    float* sv_g   = ws + 5 * ETH + 3 * BTH;
    float* r_g    = ws + 5 * ETH + 4 * BTH;        // EB*H
    float* g_g    = r_g + EBn * Hn;
    float* sh_g   = g_g + EBn * Hn;                // EB*NH
    float* o_raw  = sh_g + EBn * NHn;              // EB*H

    kA<<<Bqn * Tln, Hn, 0, stream>>>(keyval, x_k, x_v, Wk, Wv, v0, v1, v2, k_k,
                                     k_g, kk_g, vraw_g, sv_g);
    kB<<<EBn * Tln, Hn, 0, stream>>>(query, keyval, x_w, x_a, w0, w1, w2, a0, a1, a2,
                                     k_a, k_g, kk_g, vraw_g, sv_g, v_first,
                                     coef4, vt_g);
    kR<<<EBn, Hn, 0, stream>>>(query, keyval, x_r, x_g, Wr, g1, g2, r_k, coef4,
                               r_g, g_g, sh_g);
    kScan<<<EBn * NHn * VGn, 128, 0, stream>>>(coef4, vt_g, r_g, o_raw);
    kD<<<EBn, Hn, 0, stream>>>(o_raw, gn_w, gn_b, sh_g, vt_g, g_g, Wo, (float*)d_out);
}